// Round 2
// 1429.000 us; speedup vs baseline: 1.3133x; 1.3133x over previous
//
#include <hip/hip_runtime.h>
#include <cstdint>
#include <cstddef>

#define N_NODES 10000
#define DIM     3000
#define NEDGE   60000
#define EPLUS   (NEDGE + N_NODES)   /* 70000 edges incl self-loops */
#define HIDF    128
#define LATF    32
#define NHEAD   8
#define MAXDEG  256
#define NCBLK   2048
static const size_t TOTAL_NC = (size_t)N_NODES * DIM;  /* 30,000,000 */

typedef short bf16x8 __attribute__((ext_vector_type(8)));
typedef float f32x4  __attribute__((ext_vector_type(4)));

/* round-to-nearest-even fp32 -> bf16 */
__device__ __forceinline__ ushort bf16rn(float f) {
  unsigned u = __float_as_uint(f);
  return (ushort)((u + 0x7FFFu + ((u >> 16) & 1u)) >> 16);
}
__device__ __forceinline__ float bf16f(ushort h) {
  return __uint_as_float((unsigned)h << 16);
}

/* ---------------- CSR build (group edges by dst) ---------------- */
__global__ void k_count(const int* __restrict__ ei, int* __restrict__ cnt) {
  int e = blockIdx.x * blockDim.x + threadIdx.x;
  if (e >= EPLUS) return;
  int dst = (e < NEDGE) ? ei[NEDGE + e] : (e - NEDGE);
  atomicAdd(&cnt[dst], 1);
}

__global__ void k_scan(const int* __restrict__ cnt, int* __restrict__ rowptr) {
  constexpr int ITEMS = (N_NODES + 1023) / 1024;  /* 10 */
  __shared__ int s[1024];
  int t = threadIdx.x;
  int base = t * ITEMS;
  int loc[ITEMS];
  int sum = 0;
  for (int i = 0; i < ITEMS; i++) {
    int idx = base + i;
    int v = (idx < N_NODES) ? cnt[idx] : 0;
    loc[i] = sum;
    sum += v;
  }
  s[t] = sum;
  __syncthreads();
  for (int off = 1; off < 1024; off <<= 1) {
    int v = 0;
    if (t >= off) v = s[t - off];
    __syncthreads();
    if (t >= off) s[t] += v;
    __syncthreads();
  }
  int prefix = (t == 0) ? 0 : s[t - 1];
  for (int i = 0; i < ITEMS; i++) {
    int idx = base + i;
    if (idx < N_NODES) rowptr[idx] = prefix + loc[i];
  }
  if (t == 1023) rowptr[N_NODES] = prefix + sum;
}

__global__ void k_fill(const int* __restrict__ ei, const int* __restrict__ rowptr,
                       int* __restrict__ fill, int* __restrict__ esrc) {
  int e = blockIdx.x * blockDim.x + threadIdx.x;
  if (e >= EPLUS) return;
  int src, dst;
  if (e < NEDGE) { src = ei[e]; dst = ei[NEDGE + e]; }
  else           { src = e - NEDGE; dst = e - NEDGE; }
  int pos = atomicAdd(&fill[dst], 1);
  esrc[rowptr[dst] + pos] = src;
}

/* ---------------- fp32 -> 3-way bf16 split (RN), flat, n divisible by 4 ----- */
__global__ void k_split3(const float* __restrict__ src, ushort* __restrict__ ph,
                         ushort* __restrict__ pm, ushort* __restrict__ pl, size_t n4)
{
  size_t stride = (size_t)gridDim.x * blockDim.x;
  for (size_t i = (size_t)blockIdx.x * blockDim.x + threadIdx.x; i < n4; i += stride) {
    float4 v = ((const float4*)src)[i];
    float f[4] = {v.x, v.y, v.z, v.w};
    ushort hh[4], mm[4], ll[4];
#pragma unroll
    for (int j = 0; j < 4; j++) {
      ushort h = bf16rn(f[j]);
      float r1 = f[j] - bf16f(h);          /* exact (Sterbenz) */
      ushort m = bf16rn(r1);
      float r2 = r1 - bf16f(m);            /* exact */
      ushort l = bf16rn(r2);
      hh[j] = h; mm[j] = m; ll[j] = l;
    }
    ((ushort4*)ph)[i] = make_ushort4(hh[0], hh[1], hh[2], hh[3]);
    ((ushort4*)pm)[i] = make_ushort4(mm[0], mm[1], mm[2], mm[3]);
    ((ushort4*)pl)[i] = make_ushort4(ll[0], ll[1], ll[2], ll[3]);
  }
}

/* ------- weight transpose + 3-way split: W[K,Nc] -> T{h,m,l}[Nc,Ks] --------- */
__global__ void k_tsplit3(const float* __restrict__ W, ushort* __restrict__ Th,
                          ushort* __restrict__ Tm, ushort* __restrict__ Tl,
                          int K, int Nc, int Ks)
{
  __shared__ float tile[32][33];
  int tx = threadIdx.x & 31, ty = threadIdx.x >> 5;  /* 32 x 8 */
  int n0 = blockIdx.x * 32, k0 = blockIdx.y * 32;
#pragma unroll
  for (int i = 0; i < 4; i++) {
    int k = k0 + ty + i * 8, n = n0 + tx;
    tile[ty + i * 8][tx] = (k < K && n < Nc) ? W[(size_t)k * Nc + n] : 0.f;
  }
  __syncthreads();
#pragma unroll
  for (int i = 0; i < 4; i++) {
    int n = n0 + ty + i * 8, k = k0 + tx;
    if (n < Nc && k < Ks) {
      float v = tile[tx][ty + i * 8];
      ushort h = bf16rn(v);
      float r1 = v - bf16f(h);
      ushort m = bf16rn(r1);
      float r2 = r1 - bf16f(m);
      ushort l = bf16rn(r2);
      size_t o = (size_t)n * Ks + k;
      Th[o] = h; Tm[o] = m; Tl[o] = l;
    }
  }
}

/* ---- async global->LDS, 16B per lane (dest = wave-uniform base + lane*16) -- */
__device__ __forceinline__ void gld_lds16(const ushort* g, ushort* l) {
  __builtin_amdgcn_global_load_lds(
      (const __attribute__((address_space(1))) void*)g,
      (__attribute__((address_space(3))) void*)l,
      16, 0, 0);
}

/* ------------- 3-way-split bf16 MFMA GEMM, fp32-level accuracy --------------
   C = A@B^T-layout. A planes [M,lda] row-major k-contig; B planes [Nc,ldb]
   n-major k-contig (pre-transposed weights). 128x128 tile, 4 waves.
   6 products per element: hh + hm + mh + mm + hl + lh (dropped terms ~2^-27).

   Staging uses global_load_lds (width 16) into LINEAR [128][32] tiles (48KB
   total -> 3 blocks/CU). Bank-conflict fix: LDS dest stays linear (HW
   requirement); the SOURCE column slot is pre-swizzled by cc ^ ((row>>1)&3)
   and the same XOR is applied on the ds_read_b128 side (m173/m201 pattern).
   Per-8-lane bank walk is then all 32 banks -> conflict-free.
   OOB rows are clamped to the last valid row: garbage lands only in C
   rows/cols the epilogue masks; tail-K garbage in A multiplies B's zero
   padding (finite values only, so exactly 0 contribution).                  */
__global__ __launch_bounds__(256, 3) void gemm_split3(
    const ushort* __restrict__ Ah, const ushort* __restrict__ Am, const ushort* __restrict__ Al, int lda,
    const ushort* __restrict__ Bh, const ushort* __restrict__ Bm, const ushort* __restrict__ Bl, int ldb,
    const float* __restrict__ bias, float* __restrict__ C,
    int M, int Nc, int ksteps, int relu)
{
  __shared__ ushort As[3][128][32];
  __shared__ ushort Bs[3][128][32];
  int t = threadIdx.x;
  int bm = blockIdx.y * 128, bn = blockIdx.x * 128;
  int wave = t >> 6, lane = t & 63;
  int wm = (wave >> 1) * 64, wn = (wave & 1) * 64;
  int q = lane >> 4, l15 = lane & 15;

  /* staging geometry: chunk c = i*256+t; row r = c>>2, slot cc = c&3 */
  size_t offA[2], offB[2];
  int lofs[2];
#pragma unroll
  for (int i = 0; i < 2; i++) {
    int c = i * 256 + t;
    int r = c >> 2, cc = c & 3;
    int ccg = cc ^ ((r >> 1) & 3);         /* source-side swizzle */
    int ga = bm + r; if (ga > M - 1) ga = M - 1;
    int gb = bn + r; if (gb > Nc - 1) gb = Nc - 1;
    offA[i] = (size_t)ga * lda + (size_t)(ccg * 8);
    offB[i] = (size_t)gb * ldb + (size_t)(ccg * 8);
    lofs[i] = c * 8;                       /* ushort units; = lane*16B + uniform */
  }
  int fs = (q ^ ((l15 >> 1) & 3)) * 8;     /* swizzled fragment slot (ushorts) */

  f32x4 acc[4][4];
#pragma unroll
  for (int i = 0; i < 4; i++)
#pragma unroll
    for (int j = 0; j < 4; j++) acc[i][j] = (f32x4){0.f, 0.f, 0.f, 0.f};

  for (int ks = 0; ks < ksteps; ks++) {
    int k0 = ks * 32;
#pragma unroll
    for (int i = 0; i < 2; i++) {
      gld_lds16(Ah + offA[i] + k0, &As[0][0][0] + lofs[i]);
      gld_lds16(Am + offA[i] + k0, &As[1][0][0] + lofs[i]);
      gld_lds16(Al + offA[i] + k0, &As[2][0][0] + lofs[i]);
      gld_lds16(Bh + offB[i] + k0, &Bs[0][0][0] + lofs[i]);
      gld_lds16(Bm + offB[i] + k0, &Bs[1][0][0] + lofs[i]);
      gld_lds16(Bl + offB[i] + k0, &Bs[2][0][0] + lofs[i]);
    }
    __syncthreads();   /* compiler drains vmcnt(0) before s_barrier */
    bf16x8 bh[4], bmv[4], bl[4];
#pragma unroll
    for (int j = 0; j < 4; j++) {
      bh[j]  = *(const bf16x8*)&Bs[0][wn + j * 16 + l15][fs];
      bmv[j] = *(const bf16x8*)&Bs[1][wn + j * 16 + l15][fs];
      bl[j]  = *(const bf16x8*)&Bs[2][wn + j * 16 + l15][fs];
    }
#pragma unroll
    for (int i = 0; i < 4; i++) {
      bf16x8 ah = *(const bf16x8*)&As[0][wm + i * 16 + l15][fs];
      bf16x8 am = *(const bf16x8*)&As[1][wm + i * 16 + l15][fs];
      bf16x8 al = *(const bf16x8*)&As[2][wm + i * 16 + l15][fs];
#pragma unroll
      for (int j = 0; j < 4; j++) {
        acc[i][j] = __builtin_amdgcn_mfma_f32_16x16x32_bf16(ah, bh[j],  acc[i][j], 0, 0, 0);
        acc[i][j] = __builtin_amdgcn_mfma_f32_16x16x32_bf16(ah, bmv[j], acc[i][j], 0, 0, 0);
        acc[i][j] = __builtin_amdgcn_mfma_f32_16x16x32_bf16(am, bh[j],  acc[i][j], 0, 0, 0);
        acc[i][j] = __builtin_amdgcn_mfma_f32_16x16x32_bf16(am, bmv[j], acc[i][j], 0, 0, 0);
        acc[i][j] = __builtin_amdgcn_mfma_f32_16x16x32_bf16(ah, bl[j],  acc[i][j], 0, 0, 0);
        acc[i][j] = __builtin_amdgcn_mfma_f32_16x16x32_bf16(al, bh[j],  acc[i][j], 0, 0, 0);
      }
    }
    __syncthreads();
  }
  /* epilogue: D[row = q*4+r][col = l15] per 16x16 tile (m89-verified layout) */
#pragma unroll
  for (int i = 0; i < 4; i++) {
#pragma unroll
    for (int r = 0; r < 4; r++) {
      int row = bm + wm + i * 16 + q * 4 + r;
      if (row >= M) continue;
#pragma unroll
      for (int j = 0; j < 4; j++) {
        int col = bn + wn + j * 16 + l15;
        if (col >= Nc) continue;
        float v = acc[i][j][r] + (bias ? bias[col] : 0.f);
        if (relu) v = fmaxf(v, 0.f);
        C[(size_t)row * Nc + col] = v;
      }
    }
  }
}

/* ---------------- generic fp32 tiled GEMM (small layers only) ---------------- */
#define BM 64
#define BN 64
#define BK 16
__global__ __launch_bounds__(256) void gemm_f32(
    const float* __restrict__ A, const float* __restrict__ B,
    const float* __restrict__ bias, float* __restrict__ C,
    int M, int Nc, int K, int relu)
{
  __shared__ float As[BK][BM + 4];
  __shared__ float Bs[BK][BN + 4];
  int bm = blockIdx.y * BM, bn = blockIdx.x * BN;
  int t = threadIdx.x;
  int tm = (t / 16) * 4;
  int tn = (t % 16) * 4;
  float acc[4][4] = {};
  for (int k0 = 0; k0 < K; k0 += BK) {
    for (int i = t; i < BK * BM; i += 256) {
      int kk = i % BK, mm = i / BK;
      int gm = bm + mm, gk = k0 + kk;
      As[kk][mm] = (gm < M && gk < K) ? A[(size_t)gm * K + gk] : 0.f;
    }
    for (int i = t; i < BK * BN; i += 256) {
      int kk = i / BN, nn = i % BN;
      int gk = k0 + kk, gn = bn + nn;
      Bs[kk][nn] = (gk < K && gn < Nc) ? B[(size_t)gk * Nc + gn] : 0.f;
    }
    __syncthreads();
#pragma unroll
    for (int kk = 0; kk < BK; kk++) {
      float a[4], b[4];
#pragma unroll
      for (int i = 0; i < 4; i++) a[i] = As[kk][tm + i];
#pragma unroll
      for (int j = 0; j < 4; j++) b[j] = Bs[kk][tn + j];
#pragma unroll
      for (int i = 0; i < 4; i++)
#pragma unroll
        for (int j = 0; j < 4; j++) acc[i][j] += a[i] * b[j];
    }
    __syncthreads();
  }
  for (int i = 0; i < 4; i++) {
    int gm = bm + tm + i;
    if (gm >= M) continue;
    for (int j = 0; j < 4; j++) {
      int gn = bn + tn + j;
      if (gn >= Nc) continue;
      float v = acc[i][j] + (bias ? bias[gn] : 0.f);
      if (relu) v = fmaxf(v, 0.f);
      C[(size_t)gm * Nc + gn] = v;
    }
  }
}

/* ---------------- attention source/dest dot products ------------------------ */
__global__ void k_attdot(const float* __restrict__ hbuf, const float* __restrict__ a_s,
                         const float* __restrict__ a_d, float* __restrict__ as_,
                         float* __restrict__ ad_, int H, int F, int total)
{
  int wid = blockIdx.x * 4 + (threadIdx.x >> 6);
  int lane = threadIdx.x & 63;
  if (wid >= total) return;
  int h = wid % H;
  float s1 = 0.f, s2 = 0.f;
  const float* hr = hbuf + (size_t)wid * F;
  for (int f = lane; f < F; f += 64) {
    float hv = hr[f];
    s1 += hv * a_s[h * F + f];
    s2 += hv * a_d[h * F + f];
  }
  for (int off = 32; off > 0; off >>= 1) {
    s1 += __shfl_down(s1, off);
    s2 += __shfl_down(s2, off);
  }
  if (lane == 0) { as_[wid] = s1; ad_[wid] = s2; }
}

/* ---------------- GAT aggregate, H=8,F=128 ---------------------------------- */
__global__ __launch_bounds__(256) void k_gat_agg8(
    const float* __restrict__ hbuf, const float* __restrict__ as_,
    const float* __restrict__ ad_, const float* __restrict__ bias,
    const int* __restrict__ rowptr, const int* __restrict__ esrc,
    float* __restrict__ out, int relu)
{
  const int H = 8, F = 128;
  int n = blockIdx.x;
  int t = threadIdx.x;
  __shared__ float s_a[MAXDEG][8];
  __shared__ int   s_src[MAXDEG];
  __shared__ float s_out[2][128];
  int beg = rowptr[n];
  int deg = rowptr[n + 1] - beg;
  if (deg > MAXDEG) deg = MAXDEG;
  for (int j = t; j < deg; j += 256) s_src[j] = esrc[beg + j];
  __syncthreads();
  for (int idx = t; idx < deg * H; idx += 256) {
    int j = idx >> 3, h = idx & 7;
    float v = as_[(size_t)s_src[j] * H + h] + ad_[(size_t)n * H + h];
    s_a[j][h] = (v > 0.f) ? v : 0.2f * v;
  }
  __syncthreads();
  if (t < H) {
    float m = -3.4e38f;
    for (int j = 0; j < deg; j++) m = fmaxf(m, s_a[j][t]);
    float den = 0.f;
    for (int j = 0; j < deg; j++) { float e = expf(s_a[j][t] - m); s_a[j][t] = e; den += e; }
    float inv = 1.0f / (den + 1e-16f);
    for (int j = 0; j < deg; j++) s_a[j][t] *= inv;
  }
  __syncthreads();
  int f = t & 127;
  int hg = t >> 7;
  float acc = 0.f;
  for (int h = hg; h < H; h += 2)
    for (int j = 0; j < deg; j++)
      acc += s_a[j][h] * hbuf[(size_t)s_src[j] * (H * F) + h * F + f];
  s_out[hg][f] = acc;
  __syncthreads();
  if (hg == 0) {
    float v = (s_out[0][f] + s_out[1][f]) * 0.125f + bias[f];
    if (relu) v = fmaxf(v, 0.f);
    out[(size_t)n * F + f] = v;
  }
}

/* ---------------- GAT aggregate, H=1,F=32 ----------------------------------- */
__global__ void k_gat_agg1(const float* __restrict__ hbuf, const float* __restrict__ as_,
                           const float* __restrict__ ad_, const float* __restrict__ bias,
                           const int* __restrict__ rowptr, const int* __restrict__ esrc,
                           float* __restrict__ out)
{
  int n = blockIdx.x, t = threadIdx.x;  /* 64 threads */
  __shared__ float s_a[MAXDEG];
  __shared__ int   s_src[MAXDEG];
  int beg = rowptr[n];
  int deg = rowptr[n + 1] - beg;
  if (deg > MAXDEG) deg = MAXDEG;
  for (int j = t; j < deg; j += 64) {
    int s = s_src[j] = esrc[beg + j];
    float v = as_[s] + ad_[n];
    s_a[j] = (v > 0.f) ? v : 0.2f * v;
  }
  __syncthreads();
  if (t == 0) {
    float m = -3.4e38f;
    for (int j = 0; j < deg; j++) m = fmaxf(m, s_a[j]);
    float den = 0.f;
    for (int j = 0; j < deg; j++) { float e = expf(s_a[j] - m); s_a[j] = e; den += e; }
    float inv = 1.0f / (den + 1e-16f);
    for (int j = 0; j < deg; j++) s_a[j] *= inv;
  }
  __syncthreads();
  if (t < 32) {
    float acc = 0.f;
    for (int j = 0; j < deg; j++) acc += s_a[j] * hbuf[(size_t)s_src[j] * 32 + t];
    out[(size_t)n * 32 + t] = acc + bias[t];
  }
}

/* ---------------- KL head --------------------------------------------------- */
__global__ void k_kl(const float* __restrict__ z, const float* __restrict__ Wm,
                     const float* __restrict__ bm, const float* __restrict__ Wv,
                     const float* __restrict__ bv, float* __restrict__ kl)
{
  int n = blockIdx.x * 8 + (threadIdx.x >> 5);
  int l = threadIdx.x & 31;
  if (n >= N_NODES) return;
  float zm = bm[l], zv = bv[l];
  const float* zr = z + (size_t)n * LATF;
  for (int k = 0; k < LATF; k++) {
    float zk = zr[k];
    zm += zk * Wm[k * LATF + l];
    zv += zk * Wv[k * LATF + l];
  }
  float var = expf(zv);
  var = fminf(fmaxf(var, 1e-8f), 100.0f);
  float term = -0.5f * logf(var) + 0.5f * (var + zm * zm) - 0.5f;
  for (int off = 16; off > 0; off >>= 1) term += __shfl_down(term, off, 32);
  if (l == 0) kl[n] = term * 0.5f;
}

/* ---------------- row stats ------------------------------------------------- */
__global__ void k_rowstats(const float* __restrict__ recon, const float* __restrict__ x,
                           float* __restrict__ rsum, float* __restrict__ xsum,
                           float* __restrict__ regp)
{
  int n = blockIdx.x, t = threadIdx.x;
  const float* rr = recon + (size_t)n * DIM;
  const float* xr = x + (size_t)n * DIM;
  float s1 = 0.f, s2 = 0.f, sq = 0.f;
  for (int d = t; d < DIM; d += 256) {
    float r = rr[d];
    s1 += r; sq += r * r;
    s2 += xr[d];
  }
  __shared__ float sh[3][256];
  sh[0][t] = s1; sh[1][t] = s2; sh[2][t] = sq;
  __syncthreads();
  for (int off = 128; off > 0; off >>= 1) {
    if (t < off) {
      sh[0][t] += sh[0][t + off];
      sh[1][t] += sh[1][t + off];
      sh[2][t] += sh[2][t + off];
    }
    __syncthreads();
  }
  if (t == 0) { rsum[n] = sh[0][0]; xsum[n] = sh[1][0]; regp[n] = sh[2][0]; }
}

__global__ void k_reduce_reg(const float* __restrict__ regp, float* __restrict__ out_reg) {
  __shared__ double s[256];
  int t = threadIdx.x;
  double acc = 0.0;
  for (int i = t; i < N_NODES; i += 256) acc += (double)regp[i];
  s[t] = acc;
  __syncthreads();
  for (int off = 128; off > 0; off >>= 1) { if (t < off) s[t] += s[t + off]; __syncthreads(); }
  if (t == 0) out_reg[0] = (float)(s[0] * 1e-4);
}

/* ---------------- nc raw pass ----------------------------------------------- */
__global__ void k_ncraw(const float* __restrict__ recon, const float* __restrict__ rsum,
                        const float* __restrict__ xsum, float* __restrict__ ncraw,
                        float* __restrict__ pmin, float* __restrict__ pmax,
                        float* __restrict__ psum)
{
  int t = threadIdx.x;
  float lmin = 3.4e38f, lmax = -3.4e38f, lsum = 0.f;
  size_t stride = (size_t)gridDim.x * 256;
  for (size_t i = (size_t)blockIdx.x * 256 + t; i < TOTAL_NC; i += stride) {
    int n = (int)(i / DIM);
    float v = recon[i] / (rsum[n] + 1e-8f) * xsum[n];
    ncraw[i] = v;
    lmin = fminf(lmin, v); lmax = fmaxf(lmax, v); lsum += v;
  }
  __shared__ float smin[256], smax[256], ssum[256];
  smin[t] = lmin; smax[t] = lmax; ssum[t] = lsum;
  __syncthreads();
  for (int off = 128; off > 0; off >>= 1) {
    if (t < off) {
      smin[t] = fminf(smin[t], smin[t + off]);
      smax[t] = fmaxf(smax[t], smax[t + off]);
      ssum[t] += ssum[t + off];
    }
    __syncthreads();
  }
  if (t == 0) { pmin[blockIdx.x] = smin[0]; pmax[blockIdx.x] = smax[0]; psum[blockIdx.x] = ssum[0]; }
}

__global__ void k_consts(const float* __restrict__ pmin, const float* __restrict__ pmax,
                         const float* __restrict__ psum, float* __restrict__ consts)
{
  __shared__ float smin[256], smax[256];
  __shared__ double ssum[256];
  int t = threadIdx.x;
  float lmin = 3.4e38f, lmax = -3.4e38f;
  double ls = 0.0;
  for (int i = t; i < NCBLK; i += 256) {
    lmin = fminf(lmin, pmin[i]); lmax = fmaxf(lmax, pmax[i]); ls += (double)psum[i];
  }
  smin[t] = lmin; smax[t] = lmax; ssum[t] = ls;
  __syncthreads();
  for (int off = 128; off > 0; off >>= 1) {
    if (t < off) {
      smin[t] = fminf(smin[t], smin[t + off]);
      smax[t] = fmaxf(smax[t], smax[t + off]);
      ssum[t] += ssum[t + off];
    }
    __syncthreads();
  }
  if (t == 0) {
    float gmin = smin[0], gmax = smax[0];
    float meanv = (float)(ssum[0] / (double)TOTAL_NC);
    float rmin = gmin * 0.8f, rmax = gmax * 1.2f;
    float aa = (rmax - rmin) / (gmax - gmin + 1e-8f);
    float bb = rmin - aa * gmin;
    float meant = aa * meanv + bb;
    consts[0] = aa; consts[1] = bb; consts[2] = 1.0f / meant;
  }
}

__global__ void k_scale(float* __restrict__ nc, const float* __restrict__ consts) {
  float aa = consts[0], bb = consts[1], invm = consts[2];
  size_t stride = (size_t)gridDim.x * 256;
  for (size_t i = (size_t)blockIdx.x * 256 + threadIdx.x; i < TOTAL_NC; i += stride) {
    nc[i] = (aa * nc[i] + bb) * invm;
  }
}

/* =============================== launch =============================== */
extern "C" void kernel_launch(void* const* d_in, const int* in_sizes, int n_in,
                              void* d_out, int out_size, void* d_ws, size_t ws_size,
                              hipStream_t stream)
{
  const float* x   = (const float*)d_in[0];
  const int*   ei  = (const int*)d_in[1];
  const float* W1  = (const float*)d_in[3];
  const float* a1s = (const float*)d_in[4];
  const float* a1d = (const float*)d_in[5];
  const float* b1  = (const float*)d_in[6];
  const float* W2  = (const float*)d_in[7];
  const float* a2s = (const float*)d_in[8];
  const float* a2d = (const float*)d_in[9];
  const float* b2  = (const float*)d_in[10];
  const float* W3  = (const float*)d_in[11];
  const float* a3s = (const float*)d_in[12];
  const float* a3d = (const float*)d_in[13];
  const float* b3  = (const float*)d_in[14];
  const float* Wm  = (const float*)d_in[15];
  const float* bm  = (const float*)d_in[16];
  const float* Wv  = (const float*)d_in[17];
  const float* bv  = (const float*)d_in[18];
  const float* Wd1 = (const float*)d_in[19];
  const float* bd1 = (const float*)d_in[20];
  const float* Wd2 = (const float*)d_in[21];
  const float* bd2 = (const float*)d_in[22];

  float* out_nc    = (float*)d_out;                 /* 30M */
  float* out_recon = out_nc + 30000000;             /* 30M */
  float* out_kl    = out_nc + 60000000;             /* 10k */
  float* out_reg   = out_nc + 60010000;             /* 1   */

  /* ---- scratch plan (regions are dead until their late-phase writers) ----
     phase 1 (until GEMM1 done):
       out_recon[0..15M)  = xh plane (30M ushorts)
       out_recon[15M..30M)= xm plane
       out_nc[0..15M)     = xl plane
       out_nc[15M..25.24M)= h1buf (GEMM1/GEMM2 output, N x 1024 fp32)
       out_nc[25.25M..29.9M) = W1^T planes h/m/l (1024x3008 each)
     phase 2 (after GEMM1, before ncraw): out_nc[0..15M) reused for
       bufB split planes, hd split planes, W2^T planes, Wd2^T planes.
     decoder writes out_recon (xh/xm dead); ncraw writes out_nc last. */
  ushort* xh   = (ushort*)out_recon;
  ushort* xm   = (ushort*)(out_recon + 15000000);
  ushort* xl   = (ushort*)out_nc;
  float*  h1buf = out_nc + 15000000;
  ushort* W1h  = (ushort*)(out_nc + 25250000);
  ushort* W1m  = (ushort*)(out_nc + 26800000);
  ushort* W1l  = (ushort*)(out_nc + 28350000);
  ushort* bBh  = (ushort*)(out_nc + 0);        /* 10000x128 each */
  ushort* bBm  = (ushort*)(out_nc + 700000);
  ushort* bBl  = (ushort*)(out_nc + 1400000);
  ushort* hdh  = (ushort*)(out_nc + 2100000);
  ushort* hdm  = (ushort*)(out_nc + 2800000);
  ushort* hdl  = (ushort*)(out_nc + 3500000);
  ushort* Wd2h = (ushort*)(out_nc + 4500000);  /* 3008x128 each */
  ushort* Wd2m = (ushort*)(out_nc + 4700000);
  ushort* Wd2l = (ushort*)(out_nc + 4900000);
  ushort* W2h  = (ushort*)(out_nc + 5200000);  /* 1024x128 each */
  ushort* W2m  = (ushort*)(out_nc + 5300000);
  ushort* W2l  = (ushort*)(out_nc + 5400000);

  float* wsf    = (float*)d_ws;
  float* bufB   = wsf + 0;        /* N x 128 fp32 */
  float* bufC   = wsf + 1300000;  /* N x 128 fp32 */
  float* hd     = wsf + 2600000;  /* N x 128 fp32 */
  float* as_    = wsf + 3900000;  /* N x 8 */
  float* ad_    = wsf + 4000000;  /* N x 8 */
  float* zbuf   = wsf + 4100000;  /* N x 32 */
  float* h3h    = wsf + 4450000;  /* N x 32 */
  float* rsum   = wsf + 4800000;
  float* xsum   = wsf + 4820000;
  float* regp   = wsf + 4840000;
  float* pminb  = wsf + 4860000;
  float* pmaxb  = wsf + 4880000;
  float* psumb  = wsf + 4900000;
  float* consts = wsf + 4920000;
  int* rowptr = (int*)(wsf + 5000000);
  int* cntb   = rowptr + 10016;
  int* esrc   = cntb + 10016;     /* EPLUS ints; ws total ~20.4 MB */

  /* ---- prep: x split, W1 transpose-split, CSR ---- */
  k_split3<<<4096, 256, 0, stream>>>(x, xh, xm, xl, 30000000 / 4);
  k_tsplit3<<<dim3(32, 94), 256, 0, stream>>>(W1, W1h, W1m, W1l, 3000, 1024, 3008);
  hipMemsetAsync(cntb, 0, N_NODES * sizeof(int), stream);
  k_count<<<(EPLUS + 255) / 256, 256, 0, stream>>>(ei, cntb);
  k_scan<<<1, 1024, 0, stream>>>(cntb, rowptr);
  hipMemsetAsync(cntb, 0, N_NODES * sizeof(int), stream);
  k_fill<<<(EPLUS + 255) / 256, 256, 0, stream>>>(ei, rowptr, cntb, esrc);

  /* ---- GAT layer 1: x[10000,3000] @ W1 -> h1buf[10000,1024] (MFMA split3) ---- */
  gemm_split3<<<dim3(8, 79), 256, 0, stream>>>(xh, xm, xl, 3000, W1h, W1m, W1l, 3008,
                                               nullptr, h1buf, N_NODES, 1024, 94, 0);
  k_attdot<<<(N_NODES * NHEAD + 3) / 4, 256, 0, stream>>>(h1buf, a1s, a1d, as_, ad_, NHEAD, HIDF, N_NODES * NHEAD);
  k_gat_agg8<<<N_NODES, 256, 0, stream>>>(h1buf, as_, ad_, b1, rowptr, esrc, bufB, 1);

  /* ---- GAT layer 2: bufB[10000,128] @ W2 (MFMA split3). xl dead now. ---- */
  k_tsplit3<<<dim3(32, 4), 256, 0, stream>>>(W2, W2h, W2m, W2l, 128, 1024, 128);
  k_split3<<<512, 256, 0, stream>>>(bufB, bBh, bBm, bBl, 1280000 / 4);
  gemm_split3<<<dim3(8, 79), 256, 0, stream>>>(bBh, bBm, bBl, 128, W2h, W2m, W2l, 128,
                                               nullptr, h1buf, N_NODES, 1024, 4, 0);
  k_attdot<<<(N_NODES * NHEAD + 3) / 4, 256, 0, stream>>>(h1buf, a2s, a2d, as_, ad_, NHEAD, HIDF, N_NODES * NHEAD);
  k_gat_agg8<<<N_NODES, 256, 0, stream>>>(h1buf, as_, ad_, b2, rowptr, esrc, bufC, 1);

  /* ---- GAT layer 3: 128 -> 32, 1 head (fp32, tiny) ---- */
  gemm_f32<<<dim3(1, (N_NODES + BM - 1) / BM), 256, 0, stream>>>(bufC, W3, nullptr, h3h, N_NODES, LATF, HIDF, 0);
  k_attdot<<<(N_NODES + 3) / 4, 256, 0, stream>>>(h3h, a3s, a3d, as_, ad_, 1, LATF, N_NODES);
  k_gat_agg1<<<N_NODES, 64, 0, stream>>>(h3h, as_, ad_, b3, rowptr, esrc, zbuf);

  /* ---- KL head ---- */
  k_kl<<<(N_NODES + 7) / 8, 256, 0, stream>>>(zbuf, Wm, bm, Wv, bv, out_kl);

  /* ---- decoder: z@Wd1 relu (fp32, tiny) then hd@Wd2 (MFMA split3) ---- */
  gemm_f32<<<dim3(2, (N_NODES + BM - 1) / BM), 256, 0, stream>>>(zbuf, Wd1, bd1, hd, N_NODES, HIDF, LATF, 1);
  k_split3<<<512, 256, 0, stream>>>(hd, hdh, hdm, hdl, 1280000 / 4);
  k_tsplit3<<<dim3(94, 4), 256, 0, stream>>>(Wd2, Wd2h, Wd2m, Wd2l, 128, 3000, 128);
  gemm_split3<<<dim3(24, 79), 256, 0, stream>>>(hdh, hdm, hdl, 128, Wd2h, Wd2m, Wd2l, 128,
                                                bd2, out_recon, N_NODES, DIM, 4, 0);

  /* ---- nc normalization chain (MH st cancels, see round-0 analysis) ---- */
  k_rowstats<<<N_NODES, 256, 0, stream>>>(out_recon, x, rsum, xsum, regp);
  k_reduce_reg<<<1, 256, 0, stream>>>(regp, out_reg);
  k_ncraw<<<NCBLK, 256, 0, stream>>>(out_recon, rsum, xsum, out_nc, pminb, pmaxb, psumb);
  k_consts<<<1, 256, 0, stream>>>(pminb, pmaxb, psumb, consts);
  k_scale<<<4096, 256, 0, stream>>>(out_nc, consts);

  (void)in_sizes; (void)n_in; (void)out_size; (void)ws_size;
}

// Round 3
// 1271.408 us; speedup vs baseline: 1.4761x; 1.1240x over previous
//
#include <hip/hip_runtime.h>
#include <cstdint>
#include <cstddef>

#define N_NODES 10000
#define DIM     3000
#define NEDGE   60000
#define EPLUS   (NEDGE + N_NODES)   /* 70000 edges incl self-loops */
#define HIDF    128
#define LATF    32
#define NHEAD   8
#define MAXDEG  256
#define NCBLK   2048
static const size_t TOTAL_NC = (size_t)N_NODES * DIM;  /* 30,000,000 */

typedef short bf16x8 __attribute__((ext_vector_type(8)));
typedef float f32x4  __attribute__((ext_vector_type(4)));

/* round-to-nearest-even fp32 -> bf16 */
__device__ __forceinline__ ushort bf16rn(float f) {
  unsigned u = __float_as_uint(f);
  return (ushort)((u + 0x7FFFu + ((u >> 16) & 1u)) >> 16);
}
__device__ __forceinline__ float bf16f(ushort h) {
  return __uint_as_float((unsigned)h << 16);
}

/* ---------------- CSR build (group edges by dst) ---------------- */
__global__ void k_count(const int* __restrict__ ei, int* __restrict__ cnt) {
  int e = blockIdx.x * blockDim.x + threadIdx.x;
  if (e >= EPLUS) return;
  int dst = (e < NEDGE) ? ei[NEDGE + e] : (e - NEDGE);
  atomicAdd(&cnt[dst], 1);
}

__global__ void k_scan(const int* __restrict__ cnt, int* __restrict__ rowptr) {
  constexpr int ITEMS = (N_NODES + 1023) / 1024;  /* 10 */
  __shared__ int s[1024];
  int t = threadIdx.x;
  int base = t * ITEMS;
  int loc[ITEMS];
  int sum = 0;
  for (int i = 0; i < ITEMS; i++) {
    int idx = base + i;
    int v = (idx < N_NODES) ? cnt[idx] : 0;
    loc[i] = sum;
    sum += v;
  }
  s[t] = sum;
  __syncthreads();
  for (int off = 1; off < 1024; off <<= 1) {
    int v = 0;
    if (t >= off) v = s[t - off];
    __syncthreads();
    if (t >= off) s[t] += v;
    __syncthreads();
  }
  int prefix = (t == 0) ? 0 : s[t - 1];
  for (int i = 0; i < ITEMS; i++) {
    int idx = base + i;
    if (idx < N_NODES) rowptr[idx] = prefix + loc[i];
  }
  if (t == 1023) rowptr[N_NODES] = prefix + sum;
}

__global__ void k_fill(const int* __restrict__ ei, const int* __restrict__ rowptr,
                       int* __restrict__ fill, int* __restrict__ esrc) {
  int e = blockIdx.x * blockDim.x + threadIdx.x;
  if (e >= EPLUS) return;
  int src, dst;
  if (e < NEDGE) { src = ei[e]; dst = ei[NEDGE + e]; }
  else           { src = e - NEDGE; dst = e - NEDGE; }
  int pos = atomicAdd(&fill[dst], 1);
  esrc[rowptr[dst] + pos] = src;
}

/* ---------------- fp32 -> 3-way bf16 split (RN), flat, n divisible by 4 ----- */
__global__ void k_split3(const float* __restrict__ src, ushort* __restrict__ ph,
                         ushort* __restrict__ pm, ushort* __restrict__ pl, size_t n4)
{
  size_t stride = (size_t)gridDim.x * blockDim.x;
  for (size_t i = (size_t)blockIdx.x * blockDim.x + threadIdx.x; i < n4; i += stride) {
    float4 v = ((const float4*)src)[i];
    float f[4] = {v.x, v.y, v.z, v.w};
    ushort hh[4], mm[4], ll[4];
#pragma unroll
    for (int j = 0; j < 4; j++) {
      ushort h = bf16rn(f[j]);
      float r1 = f[j] - bf16f(h);          /* exact (Sterbenz) */
      ushort m = bf16rn(r1);
      float r2 = r1 - bf16f(m);            /* exact */
      ushort l = bf16rn(r2);
      hh[j] = h; mm[j] = m; ll[j] = l;
    }
    ((ushort4*)ph)[i] = make_ushort4(hh[0], hh[1], hh[2], hh[3]);
    ((ushort4*)pm)[i] = make_ushort4(mm[0], mm[1], mm[2], mm[3]);
    ((ushort4*)pl)[i] = make_ushort4(ll[0], ll[1], ll[2], ll[3]);
  }
}

/* ------- weight transpose + 3-way split: W[K,Nc] -> T{h,m,l}[Nc,Ks] --------- */
__global__ void k_tsplit3(const float* __restrict__ W, ushort* __restrict__ Th,
                          ushort* __restrict__ Tm, ushort* __restrict__ Tl,
                          int K, int Nc, int Ks)
{
  __shared__ float tile[32][33];
  int tx = threadIdx.x & 31, ty = threadIdx.x >> 5;  /* 32 x 8 */
  int n0 = blockIdx.x * 32, k0 = blockIdx.y * 32;
#pragma unroll
  for (int i = 0; i < 4; i++) {
    int k = k0 + ty + i * 8, n = n0 + tx;
    tile[ty + i * 8][tx] = (k < K && n < Nc) ? W[(size_t)k * Nc + n] : 0.f;
  }
  __syncthreads();
#pragma unroll
  for (int i = 0; i < 4; i++) {
    int n = n0 + ty + i * 8, k = k0 + tx;
    if (n < Nc && k < Ks) {
      float v = tile[tx][ty + i * 8];
      ushort h = bf16rn(v);
      float r1 = v - bf16f(h);
      ushort m = bf16rn(r1);
      float r2 = r1 - bf16f(m);
      ushort l = bf16rn(r2);
      size_t o = (size_t)n * Ks + k;
      Th[o] = h; Tm[o] = m; Tl[o] = l;
    }
  }
}

/* ---- async global->LDS, 16B per lane (dest = wave-uniform base + lane*16) -- */
__device__ __forceinline__ void gld_lds16(const ushort* g, ushort* l) {
  __builtin_amdgcn_global_load_lds(
      (const __attribute__((address_space(1))) void*)g,
      (__attribute__((address_space(3))) void*)l,
      16, 0, 0);
}

/* ------------- 3-way-split bf16 MFMA GEMM, fp32-level accuracy --------------
   C = A@B^T-layout. A planes [M,lda] row-major k-contig; B planes [Nc,ldb]
   n-major k-contig (pre-transposed weights). 128x128 tile, 4 waves.
   6 products per element: hh + hm + mh + mm + hl + lh (dropped terms ~2^-27).

   Staging uses global_load_lds (width 16) into LINEAR [128][32] tiles (48KB
   total -> 3 blocks/CU). Bank-conflict fix: LDS dest stays linear (HW
   requirement); the SOURCE column slot is pre-swizzled by cc ^ ((row>>1)&3)
   and the same XOR is applied on the ds_read_b128 side (m173/m201 pattern).

   T1 XCD-chunked blockIdx swizzle (requires nwg % 8 == 0 -- all launch
   grids here satisfy this): consecutive work ids (bn fastest) go to the
   SAME XCD, so the 8 col-blocks sharing an A-row-panel hit one L2 ->
   A fetched from HBM once instead of 8x (round-2 FETCH_SIZE evidence).

   OOB rows are clamped to the last valid row: garbage lands only in C
   rows/cols the epilogue masks; tail-K garbage in A multiplies B's zero
   padding (finite values only, so exactly 0 contribution).                  */
__global__ __launch_bounds__(256, 3) void gemm_split3(
    const ushort* __restrict__ Ah, const ushort* __restrict__ Am, const ushort* __restrict__ Al, int lda,
    const ushort* __restrict__ Bh, const ushort* __restrict__ Bm, const ushort* __restrict__ Bl, int ldb,
    const float* __restrict__ bias, float* __restrict__ C,
    int M, int Nc, int ksteps, int relu)
{
  __shared__ ushort As[3][128][32];
  __shared__ ushort Bs[3][128][32];
  int t = threadIdx.x;

  /* XCD-chunked swizzle: bid%8 ~ XCD id; give each XCD a contiguous chunk */
  int nwg = gridDim.x * gridDim.y;
  int bid = blockIdx.y * gridDim.x + blockIdx.x;
  int cpx = nwg >> 3;                       /* nwg % 8 == 0 at every call site */
  int w   = (bid & 7) * cpx + (bid >> 3);
  int bn  = (w % gridDim.x) * 128;          /* bn fastest within a chunk */
  int bm  = (w / gridDim.x) * 128;

  int wave = t >> 6, lane = t & 63;
  int wm = (wave >> 1) * 64, wn = (wave & 1) * 64;
  int q = lane >> 4, l15 = lane & 15;

  /* staging geometry: chunk c = i*256+t; row r = c>>2, slot cc = c&3 */
  size_t offA[2], offB[2];
  int lofs[2];
#pragma unroll
  for (int i = 0; i < 2; i++) {
    int c = i * 256 + t;
    int r = c >> 2, cc = c & 3;
    int ccg = cc ^ ((r >> 1) & 3);         /* source-side swizzle */
    int ga = bm + r; if (ga > M - 1) ga = M - 1;
    int gb = bn + r; if (gb > Nc - 1) gb = Nc - 1;
    offA[i] = (size_t)ga * lda + (size_t)(ccg * 8);
    offB[i] = (size_t)gb * ldb + (size_t)(ccg * 8);
    lofs[i] = c * 8;                       /* ushort units; = lane*16B + uniform */
  }
  int fs = (q ^ ((l15 >> 1) & 3)) * 8;     /* swizzled fragment slot (ushorts) */

  f32x4 acc[4][4];
#pragma unroll
  for (int i = 0; i < 4; i++)
#pragma unroll
    for (int j = 0; j < 4; j++) acc[i][j] = (f32x4){0.f, 0.f, 0.f, 0.f};

  for (int ks = 0; ks < ksteps; ks++) {
    int k0 = ks * 32;
#pragma unroll
    for (int i = 0; i < 2; i++) {
      gld_lds16(Ah + offA[i] + k0, &As[0][0][0] + lofs[i]);
      gld_lds16(Am + offA[i] + k0, &As[1][0][0] + lofs[i]);
      gld_lds16(Al + offA[i] + k0, &As[2][0][0] + lofs[i]);
      gld_lds16(Bh + offB[i] + k0, &Bs[0][0][0] + lofs[i]);
      gld_lds16(Bm + offB[i] + k0, &Bs[1][0][0] + lofs[i]);
      gld_lds16(Bl + offB[i] + k0, &Bs[2][0][0] + lofs[i]);
    }
    __syncthreads();   /* compiler drains vmcnt(0) before s_barrier */
    bf16x8 bh[4], bmv[4], bl[4];
#pragma unroll
    for (int j = 0; j < 4; j++) {
      bh[j]  = *(const bf16x8*)&Bs[0][wn + j * 16 + l15][fs];
      bmv[j] = *(const bf16x8*)&Bs[1][wn + j * 16 + l15][fs];
      bl[j]  = *(const bf16x8*)&Bs[2][wn + j * 16 + l15][fs];
    }
#pragma unroll
    for (int i = 0; i < 4; i++) {
      bf16x8 ah = *(const bf16x8*)&As[0][wm + i * 16 + l15][fs];
      bf16x8 am = *(const bf16x8*)&As[1][wm + i * 16 + l15][fs];
      bf16x8 al = *(const bf16x8*)&As[2][wm + i * 16 + l15][fs];
#pragma unroll
      for (int j = 0; j < 4; j++) {
        acc[i][j] = __builtin_amdgcn_mfma_f32_16x16x32_bf16(ah, bh[j],  acc[i][j], 0, 0, 0);
        acc[i][j] = __builtin_amdgcn_mfma_f32_16x16x32_bf16(ah, bmv[j], acc[i][j], 0, 0, 0);
        acc[i][j] = __builtin_amdgcn_mfma_f32_16x16x32_bf16(am, bh[j],  acc[i][j], 0, 0, 0);
        acc[i][j] = __builtin_amdgcn_mfma_f32_16x16x32_bf16(am, bmv[j], acc[i][j], 0, 0, 0);
        acc[i][j] = __builtin_amdgcn_mfma_f32_16x16x32_bf16(ah, bl[j],  acc[i][j], 0, 0, 0);
        acc[i][j] = __builtin_amdgcn_mfma_f32_16x16x32_bf16(al, bh[j],  acc[i][j], 0, 0, 0);
      }
    }
    __syncthreads();
  }
  /* epilogue: D[row = q*4+r][col = l15] per 16x16 tile (m89-verified layout) */
#pragma unroll
  for (int i = 0; i < 4; i++) {
#pragma unroll
    for (int r = 0; r < 4; r++) {
      int row = bm + wm + i * 16 + q * 4 + r;
      if (row >= M) continue;
#pragma unroll
      for (int j = 0; j < 4; j++) {
        int col = bn + wn + j * 16 + l15;
        if (col >= Nc) continue;
        float v = acc[i][j][r] + (bias ? bias[col] : 0.f);
        if (relu) v = fmaxf(v, 0.f);
        C[(size_t)row * Nc + col] = v;
      }
    }
  }
}

/* ---------------- generic fp32 tiled GEMM (small layers only) ---------------- */
#define BM 64
#define BN 64
#define BK 16
__global__ __launch_bounds__(256) void gemm_f32(
    const float* __restrict__ A, const float* __restrict__ B,
    const float* __restrict__ bias, float* __restrict__ C,
    int M, int Nc, int K, int relu)
{
  __shared__ float As[BK][BM + 4];
  __shared__ float Bs[BK][BN + 4];
  int bm = blockIdx.y * BM, bn = blockIdx.x * BN;
  int t = threadIdx.x;
  int tm = (t / 16) * 4;
  int tn = (t % 16) * 4;
  float acc[4][4] = {};
  for (int k0 = 0; k0 < K; k0 += BK) {
    for (int i = t; i < BK * BM; i += 256) {
      int kk = i % BK, mm = i / BK;
      int gm = bm + mm, gk = k0 + kk;
      As[kk][mm] = (gm < M && gk < K) ? A[(size_t)gm * K + gk] : 0.f;
    }
    for (int i = t; i < BK * BN; i += 256) {
      int kk = i / BN, nn = i % BN;
      int gk = k0 + kk, gn = bn + nn;
      Bs[kk][nn] = (gk < K && gn < Nc) ? B[(size_t)gk * Nc + gn] : 0.f;
    }
    __syncthreads();
#pragma unroll
    for (int kk = 0; kk < BK; kk++) {
      float a[4], b[4];
#pragma unroll
      for (int i = 0; i < 4; i++) a[i] = As[kk][tm + i];
#pragma unroll
      for (int j = 0; j < 4; j++) b[j] = Bs[kk][tn + j];
#pragma unroll
      for (int i = 0; i < 4; i++)
#pragma unroll
        for (int j = 0; j < 4; j++) acc[i][j] += a[i] * b[j];
    }
    __syncthreads();
  }
  for (int i = 0; i < 4; i++) {
    int gm = bm + tm + i;
    if (gm >= M) continue;
    for (int j = 0; j < 4; j++) {
      int gn = bn + tn + j;
      if (gn >= Nc) continue;
      float v = acc[i][j] + (bias ? bias[gn] : 0.f);
      if (relu) v = fmaxf(v, 0.f);
      C[(size_t)gm * Nc + gn] = v;
    }
  }
}

/* ---------------- attention source/dest dot products ------------------------ */
__global__ void k_attdot(const float* __restrict__ hbuf, const float* __restrict__ a_s,
                         const float* __restrict__ a_d, float* __restrict__ as_,
                         float* __restrict__ ad_, int H, int F, int total)
{
  int wid = blockIdx.x * 4 + (threadIdx.x >> 6);
  int lane = threadIdx.x & 63;
  if (wid >= total) return;
  int h = wid % H;
  float s1 = 0.f, s2 = 0.f;
  const float* hr = hbuf + (size_t)wid * F;
  for (int f = lane; f < F; f += 64) {
    float hv = hr[f];
    s1 += hv * a_s[h * F + f];
    s2 += hv * a_d[h * F + f];
  }
  for (int off = 32; off > 0; off >>= 1) {
    s1 += __shfl_down(s1, off);
    s2 += __shfl_down(s2, off);
  }
  if (lane == 0) { as_[wid] = s1; ad_[wid] = s2; }
}

/* ---------------- GAT aggregate, H=8,F=128 ---------------------------------- */
__global__ __launch_bounds__(256) void k_gat_agg8(
    const float* __restrict__ hbuf, const float* __restrict__ as_,
    const float* __restrict__ ad_, const float* __restrict__ bias,
    const int* __restrict__ rowptr, const int* __restrict__ esrc,
    float* __restrict__ out, int relu)
{
  const int H = 8, F = 128;
  int n = blockIdx.x;
  int t = threadIdx.x;
  __shared__ float s_a[MAXDEG][8];
  __shared__ int   s_src[MAXDEG];
  __shared__ float s_out[2][128];
  int beg = rowptr[n];
  int deg = rowptr[n + 1] - beg;
  if (deg > MAXDEG) deg = MAXDEG;
  for (int j = t; j < deg; j += 256) s_src[j] = esrc[beg + j];
  __syncthreads();
  for (int idx = t; idx < deg * H; idx += 256) {
    int j = idx >> 3, h = idx & 7;
    float v = as_[(size_t)s_src[j] * H + h] + ad_[(size_t)n * H + h];
    s_a[j][h] = (v > 0.f) ? v : 0.2f * v;
  }
  __syncthreads();
  if (t < H) {
    float m = -3.4e38f;
    for (int j = 0; j < deg; j++) m = fmaxf(m, s_a[j][t]);
    float den = 0.f;
    for (int j = 0; j < deg; j++) { float e = expf(s_a[j][t] - m); s_a[j][t] = e; den += e; }
    float inv = 1.0f / (den + 1e-16f);
    for (int j = 0; j < deg; j++) s_a[j][t] *= inv;
  }
  __syncthreads();
  int f = t & 127;
  int hg = t >> 7;
  float acc = 0.f;
  for (int h = hg; h < H; h += 2)
    for (int j = 0; j < deg; j++)
      acc += s_a[j][h] * hbuf[(size_t)s_src[j] * (H * F) + h * F + f];
  s_out[hg][f] = acc;
  __syncthreads();
  if (hg == 0) {
    float v = (s_out[0][f] + s_out[1][f]) * 0.125f + bias[f];
    if (relu) v = fmaxf(v, 0.f);
    out[(size_t)n * F + f] = v;
  }
}

/* ---------------- GAT aggregate, H=1,F=32 ----------------------------------- */
__global__ void k_gat_agg1(const float* __restrict__ hbuf, const float* __restrict__ as_,
                           const float* __restrict__ ad_, const float* __restrict__ bias,
                           const int* __restrict__ rowptr, const int* __restrict__ esrc,
                           float* __restrict__ out)
{
  int n = blockIdx.x, t = threadIdx.x;  /* 64 threads */
  __shared__ float s_a[MAXDEG];
  __shared__ int   s_src[MAXDEG];
  int beg = rowptr[n];
  int deg = rowptr[n + 1] - beg;
  if (deg > MAXDEG) deg = MAXDEG;
  for (int j = t; j < deg; j += 64) {
    int s = s_src[j] = esrc[beg + j];
    float v = as_[s] + ad_[n];
    s_a[j] = (v > 0.f) ? v : 0.2f * v;
  }
  __syncthreads();
  if (t == 0) {
    float m = -3.4e38f;
    for (int j = 0; j < deg; j++) m = fmaxf(m, s_a[j]);
    float den = 0.f;
    for (int j = 0; j < deg; j++) { float e = expf(s_a[j] - m); s_a[j] = e; den += e; }
    float inv = 1.0f / (den + 1e-16f);
    for (int j = 0; j < deg; j++) s_a[j] *= inv;
  }
  __syncthreads();
  if (t < 32) {
    float acc = 0.f;
    for (int j = 0; j < deg; j++) acc += s_a[j] * hbuf[(size_t)s_src[j] * 32 + t];
    out[(size_t)n * 32 + t] = acc + bias[t];
  }
}

/* ---------------- KL head --------------------------------------------------- */
__global__ void k_kl(const float* __restrict__ z, const float* __restrict__ Wm,
                     const float* __restrict__ bm, const float* __restrict__ Wv,
                     const float* __restrict__ bv, float* __restrict__ kl)
{
  int n = blockIdx.x * 8 + (threadIdx.x >> 5);
  int l = threadIdx.x & 31;
  if (n >= N_NODES) return;
  float zm = bm[l], zv = bv[l];
  const float* zr = z + (size_t)n * LATF;
  for (int k = 0; k < LATF; k++) {
    float zk = zr[k];
    zm += zk * Wm[k * LATF + l];
    zv += zk * Wv[k * LATF + l];
  }
  float var = expf(zv);
  var = fminf(fmaxf(var, 1e-8f), 100.0f);
  float term = -0.5f * logf(var) + 0.5f * (var + zm * zm) - 0.5f;
  for (int off = 16; off > 0; off >>= 1) term += __shfl_down(term, off, 32);
  if (l == 0) kl[n] = term * 0.5f;
}

/* ---------------- row stats ------------------------------------------------- */
__global__ void k_rowstats(const float* __restrict__ recon, const float* __restrict__ x,
                           float* __restrict__ rsum, float* __restrict__ xsum,
                           float* __restrict__ regp)
{
  int n = blockIdx.x, t = threadIdx.x;
  const float* rr = recon + (size_t)n * DIM;
  const float* xr = x + (size_t)n * DIM;
  float s1 = 0.f, s2 = 0.f, sq = 0.f;
  for (int d = t; d < DIM; d += 256) {
    float r = rr[d];
    s1 += r; sq += r * r;
    s2 += xr[d];
  }
  __shared__ float sh[3][256];
  sh[0][t] = s1; sh[1][t] = s2; sh[2][t] = sq;
  __syncthreads();
  for (int off = 128; off > 0; off >>= 1) {
    if (t < off) {
      sh[0][t] += sh[0][t + off];
      sh[1][t] += sh[1][t + off];
      sh[2][t] += sh[2][t + off];
    }
    __syncthreads();
  }
  if (t == 0) { rsum[n] = sh[0][0]; xsum[n] = sh[1][0]; regp[n] = sh[2][0]; }
}

__global__ void k_reduce_reg(const float* __restrict__ regp, float* __restrict__ out_reg) {
  __shared__ double s[256];
  int t = threadIdx.x;
  double acc = 0.0;
  for (int i = t; i < N_NODES; i += 256) acc += (double)regp[i];
  s[t] = acc;
  __syncthreads();
  for (int off = 128; off > 0; off >>= 1) { if (t < off) s[t] += s[t + off]; __syncthreads(); }
  if (t == 0) out_reg[0] = (float)(s[0] * 1e-4);
}

/* ---------------- nc raw pass ----------------------------------------------- */
__global__ void k_ncraw(const float* __restrict__ recon, const float* __restrict__ rsum,
                        const float* __restrict__ xsum, float* __restrict__ ncraw,
                        float* __restrict__ pmin, float* __restrict__ pmax,
                        float* __restrict__ psum)
{
  int t = threadIdx.x;
  float lmin = 3.4e38f, lmax = -3.4e38f, lsum = 0.f;
  size_t stride = (size_t)gridDim.x * 256;
  for (size_t i = (size_t)blockIdx.x * 256 + t; i < TOTAL_NC; i += stride) {
    int n = (int)(i / DIM);
    float v = recon[i] / (rsum[n] + 1e-8f) * xsum[n];
    ncraw[i] = v;
    lmin = fminf(lmin, v); lmax = fmaxf(lmax, v); lsum += v;
  }
  __shared__ float smin[256], smax[256], ssum[256];
  smin[t] = lmin; smax[t] = lmax; ssum[t] = lsum;
  __syncthreads();
  for (int off = 128; off > 0; off >>= 1) {
    if (t < off) {
      smin[t] = fminf(smin[t], smin[t + off]);
      smax[t] = fmaxf(smax[t], smax[t + off]);
      ssum[t] += ssum[t + off];
    }
    __syncthreads();
  }
  if (t == 0) { pmin[blockIdx.x] = smin[0]; pmax[blockIdx.x] = smax[0]; psum[blockIdx.x] = ssum[0]; }
}

__global__ void k_consts(const float* __restrict__ pmin, const float* __restrict__ pmax,
                         const float* __restrict__ psum, float* __restrict__ consts)
{
  __shared__ float smin[256], smax[256];
  __shared__ double ssum[256];
  int t = threadIdx.x;
  float lmin = 3.4e38f, lmax = -3.4e38f;
  double ls = 0.0;
  for (int i = t; i < NCBLK; i += 256) {
    lmin = fminf(lmin, pmin[i]); lmax = fmaxf(lmax, pmax[i]); ls += (double)psum[i];
  }
  smin[t] = lmin; smax[t] = lmax; ssum[t] = ls;
  __syncthreads();
  for (int off = 128; off > 0; off >>= 1) {
    if (t < off) {
      smin[t] = fminf(smin[t], smin[t + off]);
      smax[t] = fmaxf(smax[t], smax[t + off]);
      ssum[t] += ssum[t + off];
    }
    __syncthreads();
  }
  if (t == 0) {
    float gmin = smin[0], gmax = smax[0];
    float meanv = (float)(ssum[0] / (double)TOTAL_NC);
    float rmin = gmin * 0.8f, rmax = gmax * 1.2f;
    float aa = (rmax - rmin) / (gmax - gmin + 1e-8f);
    float bb = rmin - aa * gmin;
    float meant = aa * meanv + bb;
    consts[0] = aa; consts[1] = bb; consts[2] = 1.0f / meant;
  }
}

__global__ void k_scale(float* __restrict__ nc, const float* __restrict__ consts) {
  float aa = consts[0], bb = consts[1], invm = consts[2];
  size_t stride = (size_t)gridDim.x * 256;
  for (size_t i = (size_t)blockIdx.x * 256 + threadIdx.x; i < TOTAL_NC; i += stride) {
    nc[i] = (aa * nc[i] + bb) * invm;
  }
}

/* =============================== launch =============================== */
extern "C" void kernel_launch(void* const* d_in, const int* in_sizes, int n_in,
                              void* d_out, int out_size, void* d_ws, size_t ws_size,
                              hipStream_t stream)
{
  const float* x   = (const float*)d_in[0];
  const int*   ei  = (const int*)d_in[1];
  const float* W1  = (const float*)d_in[3];
  const float* a1s = (const float*)d_in[4];
  const float* a1d = (const float*)d_in[5];
  const float* b1  = (const float*)d_in[6];
  const float* W2  = (const float*)d_in[7];
  const float* a2s = (const float*)d_in[8];
  const float* a2d = (const float*)d_in[9];
  const float* b2  = (const float*)d_in[10];
  const float* W3  = (const float*)d_in[11];
  const float* a3s = (const float*)d_in[12];
  const float* a3d = (const float*)d_in[13];
  const float* b3  = (const float*)d_in[14];
  const float* Wm  = (const float*)d_in[15];
  const float* bm  = (const float*)d_in[16];
  const float* Wv  = (const float*)d_in[17];
  const float* bv  = (const float*)d_in[18];
  const float* Wd1 = (const float*)d_in[19];
  const float* bd1 = (const float*)d_in[20];
  const float* Wd2 = (const float*)d_in[21];
  const float* bd2 = (const float*)d_in[22];

  float* out_nc    = (float*)d_out;                 /* 30M */
  float* out_recon = out_nc + 30000000;             /* 30M */
  float* out_kl    = out_nc + 60000000;             /* 10k */
  float* out_reg   = out_nc + 60010000;             /* 1   */

  /* ---- scratch plan (regions are dead until their late-phase writers) ----
     phase 1 (until GEMM1 done):
       out_recon[0..15M)  = xh plane (30M ushorts)
       out_recon[15M..30M)= xm plane
       out_nc[0..15M)     = xl plane
       out_nc[15M..25.24M)= h1buf (GEMM1/GEMM2 output, N x 1024 fp32)
       out_nc[25.25M..29.9M) = W1^T planes h/m/l (1024x3008 each)
     phase 2 (after GEMM1, before ncraw): out_nc[0..15M) reused for
       bufB split planes, hd split planes, W2^T planes, Wd2^T planes.
     decoder writes out_recon (xh/xm dead); ncraw writes out_nc last. */
  ushort* xh   = (ushort*)out_recon;
  ushort* xm   = (ushort*)(out_recon + 15000000);
  ushort* xl   = (ushort*)out_nc;
  float*  h1buf = out_nc + 15000000;
  ushort* W1h  = (ushort*)(out_nc + 25250000);
  ushort* W1m  = (ushort*)(out_nc + 26800000);
  ushort* W1l  = (ushort*)(out_nc + 28350000);
  ushort* bBh  = (ushort*)(out_nc + 0);        /* 10000x128 each */
  ushort* bBm  = (ushort*)(out_nc + 700000);
  ushort* bBl  = (ushort*)(out_nc + 1400000);
  ushort* hdh  = (ushort*)(out_nc + 2100000);
  ushort* hdm  = (ushort*)(out_nc + 2800000);
  ushort* hdl  = (ushort*)(out_nc + 3500000);
  ushort* Wd2h = (ushort*)(out_nc + 4500000);  /* 3008x128 each */
  ushort* Wd2m = (ushort*)(out_nc + 4700000);
  ushort* Wd2l = (ushort*)(out_nc + 4900000);
  ushort* W2h  = (ushort*)(out_nc + 5200000);  /* 1024x128 each */
  ushort* W2m  = (ushort*)(out_nc + 5300000);
  ushort* W2l  = (ushort*)(out_nc + 5400000);

  float* wsf    = (float*)d_ws;
  float* bufB   = wsf + 0;        /* N x 128 fp32 */
  float* bufC   = wsf + 1300000;  /* N x 128 fp32 */
  float* hd     = wsf + 2600000;  /* N x 128 fp32 */
  float* as_    = wsf + 3900000;  /* N x 8 */
  float* ad_    = wsf + 4000000;  /* N x 8 */
  float* zbuf   = wsf + 4100000;  /* N x 32 */
  float* h3h    = wsf + 4450000;  /* N x 32 */
  float* rsum   = wsf + 4800000;
  float* xsum   = wsf + 4820000;
  float* regp   = wsf + 4840000;
  float* pminb  = wsf + 4860000;
  float* pmaxb  = wsf + 4880000;
  float* psumb  = wsf + 4900000;
  float* consts = wsf + 4920000;
  int* rowptr = (int*)(wsf + 5000000);
  int* cntb   = rowptr + 10016;
  int* esrc   = cntb + 10016;     /* EPLUS ints; ws total ~20.4 MB */

  /* ---- prep: x split, W1 transpose-split, CSR ---- */
  k_split3<<<4096, 256, 0, stream>>>(x, xh, xm, xl, 30000000 / 4);
  k_tsplit3<<<dim3(32, 94), 256, 0, stream>>>(W1, W1h, W1m, W1l, 3000, 1024, 3008);
  hipMemsetAsync(cntb, 0, N_NODES * sizeof(int), stream);
  k_count<<<(EPLUS + 255) / 256, 256, 0, stream>>>(ei, cntb);
  k_scan<<<1, 1024, 0, stream>>>(cntb, rowptr);
  hipMemsetAsync(cntb, 0, N_NODES * sizeof(int), stream);
  k_fill<<<(EPLUS + 255) / 256, 256, 0, stream>>>(ei, rowptr, cntb, esrc);

  /* ---- GAT layer 1: x[10000,3000] @ W1 -> h1buf[10000,1024] (MFMA split3) ---- */
  gemm_split3<<<dim3(8, 79), 256, 0, stream>>>(xh, xm, xl, 3000, W1h, W1m, W1l, 3008,
                                               nullptr, h1buf, N_NODES, 1024, 94, 0);
  k_attdot<<<(N_NODES * NHEAD + 3) / 4, 256, 0, stream>>>(h1buf, a1s, a1d, as_, ad_, NHEAD, HIDF, N_NODES * NHEAD);
  k_gat_agg8<<<N_NODES, 256, 0, stream>>>(h1buf, as_, ad_, b1, rowptr, esrc, bufB, 1);

  /* ---- GAT layer 2: bufB[10000,128] @ W2 (MFMA split3). xl dead now. ---- */
  k_tsplit3<<<dim3(32, 4), 256, 0, stream>>>(W2, W2h, W2m, W2l, 128, 1024, 128);
  k_split3<<<512, 256, 0, stream>>>(bufB, bBh, bBm, bBl, 1280000 / 4);
  gemm_split3<<<dim3(8, 79), 256, 0, stream>>>(bBh, bBm, bBl, 128, W2h, W2m, W2l, 128,
                                               nullptr, h1buf, N_NODES, 1024, 4, 0);
  k_attdot<<<(N_NODES * NHEAD + 3) / 4, 256, 0, stream>>>(h1buf, a2s, a2d, as_, ad_, NHEAD, HIDF, N_NODES * NHEAD);
  k_gat_agg8<<<N_NODES, 256, 0, stream>>>(h1buf, as_, ad_, b2, rowptr, esrc, bufC, 1);

  /* ---- GAT layer 3: 128 -> 32, 1 head (fp32, tiny) ---- */
  gemm_f32<<<dim3(1, (N_NODES + BM - 1) / BM), 256, 0, stream>>>(bufC, W3, nullptr, h3h, N_NODES, LATF, HIDF, 0);
  k_attdot<<<(N_NODES + 3) / 4, 256, 0, stream>>>(h3h, a3s, a3d, as_, ad_, 1, LATF, N_NODES);
  k_gat_agg1<<<N_NODES, 64, 0, stream>>>(h3h, as_, ad_, b3, rowptr, esrc, zbuf);

  /* ---- KL head ---- */
  k_kl<<<(N_NODES + 7) / 8, 256, 0, stream>>>(zbuf, Wm, bm, Wv, bv, out_kl);

  /* ---- decoder: z@Wd1 relu (fp32, tiny) then hd@Wd2 (MFMA split3) ---- */
  gemm_f32<<<dim3(2, (N_NODES + BM - 1) / BM), 256, 0, stream>>>(zbuf, Wd1, bd1, hd, N_NODES, HIDF, LATF, 1);
  k_split3<<<512, 256, 0, stream>>>(hd, hdh, hdm, hdl, 1280000 / 4);
  k_tsplit3<<<dim3(94, 4), 256, 0, stream>>>(Wd2, Wd2h, Wd2m, Wd2l, 128, 3000, 128);
  gemm_split3<<<dim3(24, 79), 256, 0, stream>>>(hdh, hdm, hdl, 128, Wd2h, Wd2m, Wd2l, 128,
                                                bd2, out_recon, N_NODES, DIM, 4, 0);

  /* ---- nc normalization chain (MH st cancels, see round-0 analysis) ---- */
  k_rowstats<<<N_NODES, 256, 0, stream>>>(out_recon, x, rsum, xsum, regp);
  k_reduce_reg<<<1, 256, 0, stream>>>(regp, out_reg);
  k_ncraw<<<NCBLK, 256, 0, stream>>>(out_recon, rsum, xsum, out_nc, pminb, pmaxb, psumb);
  k_consts<<<1, 256, 0, stream>>>(pminb, pmaxb, psumb, consts);
  k_scale<<<4096, 256, 0, stream>>>(out_nc, consts);

  (void)in_sizes; (void)n_in; (void)out_size; (void)ws_size;
}